// Round 2
// baseline (83.571 us; speedup 1.0000x reference)
//
#include <hip/hip_runtime.h>
#include <hip/hip_bf16.h>

// Resonance synth:
//   out(b,e,n) = sum_f env_f(n) * sin(2*pi*freq_f*(n+1))
//   freq_f = (MIN + SCALE*f0_be) * (f+1), zeroed if >= 1.0
//   env_f(n) = linear frame->sample interp of res_bef^(t+1), t=0..127
//
// Round 2: no f64 in the loop (u32 fixed-point phase), no LDS at all
// (envelope endpoint follows A *= r recurrence because each k-step
// advances exactly one frame, so interp weight w is per-thread constant).

#define NSAMP 32768
#define NFRM  128
#define NF    32
#define NPAIR 64
#define CHUNKS 16
#define CHUNK (NSAMP / CHUNKS)   // 2048 samples per block
#define KIT   (CHUNK / 256)      // 8 iterations per thread

// Runtime-dtype input load: bf16 or f32, selected by wave-uniform flag.
__device__ __forceinline__ float ldin(const void* p, int i, bool isbf) {
    if (isbf) {
        unsigned int w = ((unsigned int)((const unsigned short*)p)[i]) << 16;
        float f;
        __builtin_memcpy(&f, &w, 4);
        return f;
    }
    return ((const float*)p)[i];
}

extern "C" __global__ __launch_bounds__(256)
void reson_kernel(const void* __restrict__ f0p,
                  const void* __restrict__ resp,
                  const void* __restrict__ facp,
                  void* __restrict__ outp)
{
    // dtype sniff: factors[0] == 1.0f. As f32 the first word is 0x3F800000;
    // as bf16 the first word packs (1.0bf16, 2.0bf16) = 0x40003F80.
    const bool isbf = (((const unsigned int*)facp)[0] != 0x3F800000u);

    const int pair = blockIdx.x;             // 0..63
    const int tid  = threadIdx.x;            // 0..255
    const int n0   = blockIdx.y * CHUNK + tid;

    const float MINF = (float)(40.0 / 11025.0);
    const float FSC  = (float)(3960.0 / 11025.0);

    const float f0v = ldin(f0p, pair, isbf);
    const float sf0 = MINF + FSC * f0v;

    // frame-interp coord at k=0 (align_corners=False): (n+0.5)/256 - 0.5
    const float c0raw = (n0 + 0.5f) * (1.0f / 256.0f) - 0.5f;
    float c0 = fminf(fmaxf(c0raw, 0.0f), (float)(NFRM - 1));
    const int   i0c = (int)c0;               // floor, c0 >= 0
    const float w0  = c0 - (float)i0c;
    // per-thread constant weight for k >= 1 (c advances by exactly 1/frame)
    const float c1  = c0raw + 1.0f;          // >= 0.5 always
    const int   i01 = (int)c1;
    const float w1  = c1 - (float)i01;
    const bool  clampLow = (c0raw < 0.0f);   // only block y==0, tid<128

    // Per-harmonic register state:
    //  R[f] = resonance decay,  A[f] = R^(frame_idx+1) env endpoint,
    //  Q[f] = freq in u32 fixed-point turns (2^32 = 1 revolution).
    float A[NF], R[NF];
    unsigned int Q[NF];
    #pragma unroll
    for (int f = 0; f < NF; ++f) {
        const float r = ldin(resp, pair * NF + f, isbf);
        R[f] = r;
        float fac = ldin(facp, f, isbf);
        float fr  = sf0 * fac;
        if (fr >= 1.0f) fr = 0.0f;           // alias-zeroing
        Q[f] = (unsigned int)((double)fr * 4294967296.0);  // exact in f64
        A[f] = exp2f(log2f(r) * (float)(i0c + 1));
    }

    const int obase = pair * NSAMP;

    // ---- k = 0 (handles the low-clamp transition specially) ----
    {
        unsigned int nn = (unsigned int)(n0 + 1);
        float acc = 0.0f;
        #pragma unroll
        for (int f = 0; f < NF; ++f) {
            const float An  = A[f] * R[f];
            const float env = fmaf(w0, An - A[f], A[f]);
            const unsigned int ph = Q[f] * nn;             // mod 2^32 = frac
            const float t = (float)ph * 0x1p-32f;          // turns in [0,1)
            acc = fmaf(env, __builtin_amdgcn_sinf(t), acc);
            // clamped-low threads stay on frame 0 for k=1 (i01==i0c)
            A[f] = clampLow ? A[f] : An;
        }
        const int o = obase + n0;
        if (isbf) ((__hip_bfloat16*)outp)[o] = __float2bfloat16(acc);
        else      ((float*)outp)[o] = acc;
    }

    // ---- k = 1..7: pure recurrence ----
    for (int k = 1; k < KIT; ++k) {
        const int n = n0 + k * 256;
        const unsigned int nn = (unsigned int)(n + 1);
        // high-clamp (only last iter of last chunk): env collapses to A
        const float wk = (c0raw + (float)k > (float)(NFRM - 1)) ? 0.0f : w1;
        float acc = 0.0f;
        #pragma unroll
        for (int f = 0; f < NF; ++f) {
            const float An  = A[f] * R[f];
            const float env = fmaf(wk, An - A[f], A[f]);
            const unsigned int ph = Q[f] * nn;
            const float t = (float)ph * 0x1p-32f;
            acc = fmaf(env, __builtin_amdgcn_sinf(t), acc);
            A[f] = An;
        }
        const int o = obase + n;
        if (isbf) ((__hip_bfloat16*)outp)[o] = __float2bfloat16(acc);
        else      ((float*)outp)[o] = acc;
    }
}

extern "C" void kernel_launch(void* const* d_in, const int* in_sizes, int n_in,
                              void* d_out, int out_size, void* d_ws, size_t ws_size,
                              hipStream_t stream) {
    (void)in_sizes; (void)n_in; (void)out_size; (void)d_ws; (void)ws_size;
    dim3 grid(NPAIR, CHUNKS);   // 1024 blocks, 4096 waves, 16 waves/CU
    dim3 block(256);
    reson_kernel<<<grid, block, 0, stream>>>(d_in[0], d_in[1], d_in[2], d_out);
}